// Round 10
// baseline (257.037 us; speedup 1.0000x reference)
//
#include <hip/hip_runtime.h>
#include <hip/hip_bf16.h>
#include <cstdint>

typedef __bf16 bf16;
typedef bf16 bf16x2 __attribute__((ext_vector_type(2)));
typedef bf16 bf16x4 __attribute__((ext_vector_type(4)));
typedef bf16 bf16x8 __attribute__((ext_vector_type(8)));
typedef float f32x4 __attribute__((ext_vector_type(4)));
typedef unsigned int uint32x2_t __attribute__((ext_vector_type(2)));
typedef unsigned int uint32x4_t __attribute__((ext_vector_type(4)));

#define MFMA16(a, b, c) __builtin_amdgcn_mfma_f32_16x16x32_bf16((a), (b), (c), 0, 0, 0)

// 0.125 * log2(e): folded into Q at the QKV-GEMM epilogue
#define QSCALE 0.18033688011112042f

// async global->LDS DMA, 16B/lane. LDS dest must be wave-uniform base + lane*16.
__device__ inline void async16(const bf16* g, bf16* l) {
  __builtin_amdgcn_global_load_lds(
      (const __attribute__((address_space(1))) void*)g,
      (__attribute__((address_space(3))) void*)l, 16, 0, 0);
}

// ------------------------------------------------------------------
// fused cast fp32 -> bf16 for all four inputs (one launch)
// ------------------------------------------------------------------
__global__ void cast_all(const float* __restrict__ x, const float* __restrict__ wq,
                         const float* __restrict__ wkv, const float* __restrict__ wp,
                         bf16* __restrict__ xb, bf16* __restrict__ w1b,
                         bf16* __restrict__ wpb) {
  const int i = blockIdx.x * blockDim.x + threadIdx.x;
  const float4* src;
  bf16x4* dst;
  int idx;
  if (i < 2097152) {
    src = (const float4*)x; dst = (bf16x4*)xb; idx = i;
  } else if (i < 2359296) {
    src = (const float4*)wq; dst = (bf16x4*)w1b; idx = i - 2097152;
  } else if (i < 2490368) {
    src = (const float4*)wkv; dst = (bf16x4*)(w1b + 1048576); idx = i - 2359296;
  } else {
    src = (const float4*)wp; dst = (bf16x4*)wpb; idx = i - 2490368;
  }
  const float4 v = src[idx];
  bf16x4 o;
  o.x = (bf16)v.x; o.y = (bf16)v.y; o.z = (bf16)v.z; o.w = (bf16)v.w;
  dst[idx] = o;
}

// ------------------------------------------------------------------
// GEMM1: C[m,e] = sum_c x[m,c] * W1[e,c]   (M=8192, N=1536, K=1024)
// XCD swizzle; single-buffer staging; LDS-bounce coalesced epilogue (r9 win).
// ------------------------------------------------------------------
__global__ __launch_bounds__(256, 2)
void gemm_qkv(const bf16* __restrict__ A, const bf16* __restrict__ B,
              bf16* __restrict__ qb, bf16* __restrict__ kb, bf16* __restrict__ vb) {
  constexpr int K = 1024;
  constexpr int NX = 12;
  __shared__ bf16 sA[128 * 64];
  __shared__ bf16 sB[128 * 64];
  __shared__ float sC[32 * 132];  // epilogue bounce: 32 rows x 128 e, pad 4
  const int tid = threadIdx.x;
  const int lane = tid & 63, wid = tid >> 6;
  const int col = lane & 15, quad = lane >> 4;
  const int wm = wid >> 1, wn = wid & 1;
  const int bid = blockIdx.y * NX + blockIdx.x;
  const int swz = (bid & 7) * (NX * 64 / 8) + (bid >> 3);
  const int m0 = (swz / NX) * 128, n0 = (swz % NX) * 128;
  const int c7 = col & 7;

  f32x4 acc[4][4];
  const f32x4 z = {0.f, 0.f, 0.f, 0.f};
#pragma unroll
  for (int mi = 0; mi < 4; mi++)
#pragma unroll
    for (int ni = 0; ni < 4; ni++) acc[mi][ni] = z;

  for (int k0 = 0; k0 < K; k0 += 64) {
    __syncthreads();
#pragma unroll
    for (int c = 0; c < 4; ++c) {
      const int idx = c * 256 + tid;
      const int row = idx >> 3, kc = idx & 7;
      const int gkc = kc ^ (row & 7);
      async16(&A[(size_t)(m0 + row) * K + k0 + gkc * 8], &sA[idx * 8]);
      async16(&B[(size_t)(n0 + row) * K + k0 + gkc * 8], &sB[idx * 8]);
    }
    __syncthreads();  // vmcnt(0) drain: DMA complete
#pragma unroll
    for (int ks = 0; ks < 2; ++ks) {
      bf16x8 af[4], bfr[4];
#pragma unroll
      for (int i = 0; i < 4; i++)
        af[i] = *(const bf16x8*)&sA[(wm * 64 + i * 16 + col) * 64 +
                                    (((ks * 4 + quad) ^ c7) << 3)];
#pragma unroll
      for (int i = 0; i < 4; i++)
        bfr[i] = *(const bf16x8*)&sB[(wn * 64 + i * 16 + col) * 64 +
                                     (((ks * 4 + quad) ^ c7) << 3)];
#pragma unroll
      for (int mi = 0; mi < 4; mi++)
#pragma unroll
        for (int ni = 0; ni < 4; ni++)
          acc[mi][ni] = MFMA16(af[mi], bfr[ni], acc[mi][ni]);
    }
  }

  // ---- LDS-bounce epilogue: 4 phases of 32 m-rows ----
  const int erow = tid >> 3, ecg = tid & 7;
  const int gmb = m0 + (erow >> 4) * 64 + (erow & 15);
  const int ge0 = n0 + ecg * 16;
  const float sc = (ge0 < 1024) ? QSCALE : 1.0f;
#pragma unroll
  for (int mi = 0; mi < 4; mi++) {
    __syncthreads();
    {
      const int lrow = wm * 16 + quad * 4;
#pragma unroll
      for (int ni = 0; ni < 4; ni++) {
        const int lcol = wn * 64 + ni * 16 + col;
#pragma unroll
        for (int r = 0; r < 4; r++) sC[(lrow + r) * 132 + lcol] = acc[mi][ni][r];
      }
    }
    __syncthreads();
    const float4 v0 = *(const float4*)&sC[erow * 132 + ecg * 16];
    const float4 v1 = *(const float4*)&sC[erow * 132 + ecg * 16 + 4];
    const float4 v2 = *(const float4*)&sC[erow * 132 + ecg * 16 + 8];
    const float4 v3 = *(const float4*)&sC[erow * 132 + ecg * 16 + 12];
    bf16x8 o0, o1;
    o0[0] = (bf16)(v0.x * sc); o0[1] = (bf16)(v0.y * sc);
    o0[2] = (bf16)(v0.z * sc); o0[3] = (bf16)(v0.w * sc);
    o0[4] = (bf16)(v1.x * sc); o0[5] = (bf16)(v1.y * sc);
    o0[6] = (bf16)(v1.z * sc); o0[7] = (bf16)(v1.w * sc);
    o1[0] = (bf16)(v2.x * sc); o1[1] = (bf16)(v2.y * sc);
    o1[2] = (bf16)(v2.z * sc); o1[3] = (bf16)(v2.w * sc);
    o1[4] = (bf16)(v3.x * sc); o1[5] = (bf16)(v3.y * sc);
    o1[6] = (bf16)(v3.z * sc); o1[7] = (bf16)(v3.w * sc);
    const int m = gmb + mi * 16;
    const int bb = m >> 11, t = m & 2047;
    bf16* dst;
    if (ge0 < 1024) {
      dst = &qb[(((size_t)bb * 16 + (ge0 >> 6)) * 2048 + t) * 64 + (ge0 & 63)];
    } else if (ge0 < 1280) {
      const int f = ge0 - 1024;
      dst = &kb[(((size_t)bb * 4 + (f >> 6)) * 2048 + t) * 64 + (f & 63)];
    } else {
      const int f = ge0 - 1280;
      dst = &vb[(((size_t)bb * 4 + (f >> 6)) * 2048 + t) * 64 + (f & 63)];
    }
    *(bf16x8*)dst = o0;
    *(bf16x8*)(dst + 8) = o1;
  }
}

// ------------------------------------------------------------------
// GEMM2: out[m,e] = sum_c AO[m,c] * Wproj[e,c] + bias[e]  (fp32 out)
// ------------------------------------------------------------------
__global__ __launch_bounds__(256, 2)
void gemm_proj(const bf16* __restrict__ A, const bf16* __restrict__ B,
               const float* __restrict__ bias, float* __restrict__ out) {
  constexpr int K = 1024;
  constexpr int NX = 8;
  __shared__ bf16 sA[128 * 64];
  __shared__ bf16 sB[128 * 64];
  const int tid = threadIdx.x;
  const int lane = tid & 63, wid = tid >> 6;
  const int col = lane & 15, quad = lane >> 4;
  const int wm = wid >> 1, wn = wid & 1;
  const int bid = blockIdx.y * NX + blockIdx.x;
  const int swz = (bid & 7) * (NX * 64 / 8) + (bid >> 3);
  const int m0 = (swz / NX) * 128, n0 = (swz % NX) * 128;
  const int c7 = col & 7;

  f32x4 acc[4][4];
  const f32x4 z = {0.f, 0.f, 0.f, 0.f};
#pragma unroll
  for (int mi = 0; mi < 4; mi++)
#pragma unroll
    for (int ni = 0; ni < 4; ni++) acc[mi][ni] = z;

  for (int k0 = 0; k0 < K; k0 += 64) {
    __syncthreads();
#pragma unroll
    for (int c = 0; c < 4; ++c) {
      const int idx = c * 256 + tid;
      const int row = idx >> 3, kc = idx & 7;
      const int gkc = kc ^ (row & 7);
      async16(&A[(size_t)(m0 + row) * K + k0 + gkc * 8], &sA[idx * 8]);
      async16(&B[(size_t)(n0 + row) * K + k0 + gkc * 8], &sB[idx * 8]);
    }
    __syncthreads();
#pragma unroll
    for (int ks = 0; ks < 2; ++ks) {
      bf16x8 af[4], bfr[4];
#pragma unroll
      for (int i = 0; i < 4; i++)
        af[i] = *(const bf16x8*)&sA[(wm * 64 + i * 16 + col) * 64 +
                                    (((ks * 4 + quad) ^ c7) << 3)];
#pragma unroll
      for (int i = 0; i < 4; i++)
        bfr[i] = *(const bf16x8*)&sB[(wn * 64 + i * 16 + col) * 64 +
                                     (((ks * 4 + quad) ^ c7) << 3)];
#pragma unroll
      for (int mi = 0; mi < 4; mi++)
#pragma unroll
        for (int ni = 0; ni < 4; ni++)
          acc[mi][ni] = MFMA16(af[mi], bfr[ni], acc[mi][ni]);
    }
  }
#pragma unroll
  for (int mi = 0; mi < 4; mi++) {
#pragma unroll
    for (int ni = 0; ni < 4; ni++) {
      const int e = n0 + wn * 64 + ni * 16 + col;
      const float be = bias[e];
#pragma unroll
      for (int r = 0; r < 4; r++) {
        const int m = m0 + wm * 64 + mi * 16 + quad * 4 + r;
        out[(size_t)m * 1024 + e] = acc[mi][ni][r] + be;
      }
    }
  }
}

// ==================================================================
// Flash attention, ALiBi bias, fixed-max softmax, transposed dataflow.
// Round-10: 512-THREAD BLOCKS, 8 waves x 32 q-rows each; SAME 512-block
// grid, SAME 34.8KB LDS and staging per block (this is the r2 idea done
// right: r2 doubled blocks -> doubled staging/FETCH; here staging is
// SHARED across 8 waves, so total work is identical to the 105us kernel
// while per-wave register state ~halves -> natural 4 waves/SIMD tier).
// Role-split staging: waves 0-3 stage V (regs->LDS transpose), waves
// 4-7 issue the K global_load_lds DMAs. Same buffer-safety invariant.
// NO launch-bounds cap (r3 lesson), NO setprio (r6 lesson).
// 32-q compute body verbatim from r2 (harness-verified).
// ==================================================================
#define SM32(kp_)                                                           \
  _Pragma("unroll")                                                         \
  for (int ni = 0; ni < 2; ni++) {                                          \
    unsigned plo[2], phi[2];                                                \
    _Pragma("unroll")                                                       \
    for (int t = 0; t < 2; t++) {                                           \
      const int mi = (kp_) * 2 + t;                                         \
      const int U = c0 + mi * 16 - qbase - ni * 16;                         \
      f32x4 p;                                                              \
      if (U <= -15) {                                                       \
        const float bb = cb * (float)(U + qoff);                            \
        _Pragma("unroll")                                                   \
        for (int r = 0; r < 4; r++)                                         \
          p[r] = __builtin_amdgcn_exp2f(S[mi][ni][r] + (bb + cb * (float)r)); \
      } else if (U >= 16) {                                                 \
        _Pragma("unroll")                                                   \
        for (int r = 0; r < 4; r++)                                         \
          p[r] = __builtin_amdgcn_exp2f(S[mi][ni][r]);                      \
      } else {                                                              \
        const float relf = (float)(U + qoff);                               \
        _Pragma("unroll")                                                   \
        for (int r = 0; r < 4; r++) {                                       \
          const float rr = relf + (float)r;                                 \
          const float bb = (rr <= 0.f) ? cb * rr : 0.f;                     \
          p[r] = __builtin_amdgcn_exp2f(S[mi][ni][r] + bb);                 \
        }                                                                   \
      }                                                                     \
      bf16x2 lo, hi;                                                        \
      lo.x = (bf16)p[0]; lo.y = (bf16)p[1];                                 \
      hi.x = (bf16)p[2]; hi.y = (bf16)p[3];                                 \
      plo[t] = __builtin_bit_cast(unsigned, lo);                            \
      phi[t] = __builtin_bit_cast(unsigned, hi);                            \
    }                                                                       \
    uint32x2_t rl = __builtin_amdgcn_permlane32_swap(plo[0], plo[1], false, false); \
    uint32x2_t rh = __builtin_amdgcn_permlane32_swap(phi[0], phi[1], false, false); \
    uint32x2_t w02 = __builtin_amdgcn_permlane16_swap(rl.x, rl.y, false, false);    \
    uint32x2_t w13 = __builtin_amdgcn_permlane16_swap(rh.x, rh.y, false, false);    \
    uint32x4_t W;                                                           \
    W.x = w02.x; W.y = w13.x; W.z = w02.y; W.w = w13.y;                     \
    ap[ni][kp_] = __builtin_bit_cast(bf16x8, W);                            \
  }

#define PV32(kp_)                                                           \
  {                                                                         \
    bf16x8 bv[4];                                                           \
    _Pragma("unroll")                                                       \
    for (int nd = 0; nd < 4; nd++) {                                        \
      const int d = nd * 16 + col;                                          \
      bv[nd] = *(const bf16x8*)&svw[d * 72 +                                \
                   ((((kp_) * 4 + quad) ^ (d >> 3)) << 3)];                 \
    }                                                                       \
    _Pragma("unroll")                                                       \
    for (int qi = 0; qi < 2; qi++) {                                        \
      _Pragma("unroll")                                                     \
      for (int nd = 0; nd < 4; nd++)                                        \
        O[qi][nd] = MFMA16(ap[qi][kp_], bv[nd], O[qi][nd]);                 \
      Osum[qi] = MFMA16(ap[qi][kp_], bones, Osum[qi]);                      \
    }                                                                       \
  }

__global__ __launch_bounds__(512)
void attn_alibi(const bf16* __restrict__ qb, const bf16* __restrict__ kb,
                const bf16* __restrict__ vb, bf16* __restrict__ ob) {
  __shared__ bf16 sK[2][64 * 64];   // [buf][kv][d], xor-swizzled stride 64 (DMA)
  __shared__ bf16 sVt[2][64 * 72];  // [buf][d][kv], stride 72, kv-block xor-swizzle
  const int tid = threadIdx.x;
  const int lane = tid & 63, wid = tid >> 6;  // wid 0..7
  const int col = lane & 15, quad = lane >> 4;
  const int c7 = col & 7;
  const int bh = blockIdx.y;
  const int b = bh >> 4, h = bh & 15, kvh = h & 3;
  const int qbase = __builtin_amdgcn_readfirstlane(blockIdx.x * 256 + wid * 32);

  const bf16* qptr = qb + ((size_t)(b * 16 + h) * 2048 + qbase) * 64;
  const bf16* kptr = kb + ((size_t)(b * 4 + kvh) * 2048) * 64;
  const bf16* vptr = vb + ((size_t)(b * 4 + kvh) * 2048) * 64;

  // Q resident as B-operand frags: B[n=q (col)][k=d]   (2 q-tiles per wave)
  bf16x8 bq[2][2];
#pragma unroll
  for (int ni = 0; ni < 2; ni++)
#pragma unroll
    for (int ks = 0; ks < 2; ks++)
      bq[ni][ks] = *(const bf16x8*)&qptr[(ni * 16 + col) * 64 + ks * 32 + quad * 8];

  // all-ones B-frag for MFMA row sums
  bf16x8 bones;
#pragma unroll
  for (int j = 0; j < 8; j++) bones[j] = (bf16)1.0f;

  f32x4 O[2][4];
  f32x4 Osum[2];
  const f32x4 z = {0.f, 0.f, 0.f, 0.f};
#pragma unroll
  for (int qi = 0; qi < 2; qi++) {
    Osum[qi] = z;
#pragma unroll
    for (int nd = 0; nd < 4; nd++) O[qi][nd] = z;
  }

  const float cb = exp2f(-0.5f * (float)(h + 1)) * QSCALE;
  const int qoff = quad * 4 - col;

  // role-split staging coords (256 threads per role)
  const bool vrole = (wid < 4);
  const int t8 = tid & 255;
  const int rowA = t8 >> 3, kc = t8 & 7;
  const int kxA = (kc ^ (rowA & 7)) << 3;  // (rowA+32)&7 == rowA&7
  const int rv = rowA * 2;
  const int blkv = rv >> 3, rlv = rv & 7;

  // prologue: waves 4-7 DMA K(0); waves 0-3 load V(0) into regs
  bf16x8 vr0, vr1;
  if (vrole) {
    vr0 = *(const bf16x8*)&vptr[(size_t)rv * 64 + kc * 8];
    vr1 = *(const bf16x8*)&vptr[(size_t)(rv + 1) * 64 + kc * 8];
  } else {
    async16(&kptr[(size_t)rowA * 64 + kxA], &sK[0][t8 * 8]);
    async16(&kptr[(size_t)(rowA + 32) * 64 + kxA], &sK[0][(256 + t8) * 8]);
  }

  int bufi = 0;
  for (int c0 = 0; c0 < 2048; c0 += 64, bufi ^= 1) {
    bf16* skw = sK[bufi];
    bf16* svw = sVt[bufi];
    // waves 0-3 commit prefetched V regs (transposed, swizzled)
    if (vrole) {
#pragma unroll
      for (int j = 0; j < 8; j++) {
        bf16x2 pr;
        pr.x = vr0[j];
        pr.y = vr1[j];
        *(bf16x2*)&svw[(kc * 8 + j) * 72 + ((blkv ^ kc) << 3) + rlv] = pr;
      }
    }
    __syncthreads();  // K DMA drained (issuing waves), V writes visible

    // issue next chunk's staging — compute phase covers the latency
    {
      const int cn = (c0 + 64 < 2048) ? c0 + 64 : 0;
      if (vrole) {
        vr0 = *(const bf16x8*)&vptr[(size_t)(cn + rv) * 64 + kc * 8];
        vr1 = *(const bf16x8*)&vptr[(size_t)(cn + rv + 1) * 64 + kc * 8];
      } else {
        bf16* skn = sK[bufi ^ 1];
        async16(&kptr[(size_t)(cn + rowA) * 64 + kxA], &skn[t8 * 8]);
        async16(&kptr[(size_t)(cn + rowA + 32) * 64 + kxA], &skn[(256 + t8) * 8]);
      }
    }

    // S^T = K Q^T : rows=kv, cols=q (Q pre-scaled: exp2 domain)
    f32x4 S[4][2];
    {
      bf16x8 ak[4];
#pragma unroll
      for (int mi = 0; mi < 4; mi++)
        ak[mi] = *(const bf16x8*)&skw[(mi * 16 + col) * 64 + ((quad ^ c7) << 3)];
#pragma unroll
      for (int mi = 0; mi < 4; mi++)
#pragma unroll
        for (int ni = 0; ni < 2; ni++)
          S[mi][ni] = MFMA16(ak[mi], bq[ni][0], z);
#pragma unroll
      for (int mi = 0; mi < 4; mi++)
        ak[mi] = *(const bf16x8*)&skw[(mi * 16 + col) * 64 + (((4 + quad) ^ c7) << 3)];
#pragma unroll
      for (int mi = 0; mi < 4; mi++)
#pragma unroll
        for (int ni = 0; ni < 2; ni++)
          S[mi][ni] = MFMA16(ak[mi], bq[ni][1], S[mi][ni]);
    }

    // hazard-free interleave (no fences): SM32(1) regs disjoint from PV32(0) sources
    bf16x8 ap[2][2];
    SM32(0);
    PV32(0);
    SM32(1);
    PV32(1);
  }

  // epilogue: every lane holds its row sum in Osum[qi][r]
#pragma unroll
  for (int qi = 0; qi < 2; qi++) {
#pragma unroll
    for (int r = 0; r < 4; r++) {
      const float inv = 1.0f / Osum[qi][r];
      const int t = qbase + qi * 16 + quad * 4 + r;
#pragma unroll
      for (int nd = 0; nd < 4; nd++) {
        ob[((size_t)b * 2048 + t) * 1024 + h * 64 + nd * 16 + col] =
            (bf16)(O[qi][nd][r] * inv);
      }
    }
  }
}

// ------------------------------------------------------------------
extern "C" void kernel_launch(void* const* d_in, const int* in_sizes, int n_in,
                              void* d_out, int out_size, void* d_ws, size_t ws_size,
                              hipStream_t stream) {
  const float* x     = (const float*)d_in[0];
  const float* Wq    = (const float*)d_in[1];
  const float* Wkv   = (const float*)d_in[2];
  const float* Wproj = (const float*)d_in[3];
  const float* bproj = (const float*)d_in[4];
  float* out = (float*)d_out;

  bf16* xb  = (bf16*)d_ws;            // 8192*1024
  bf16* w1b = xb  + 8388608;          // 1536*1024
  bf16* wpb = w1b + 1572864;          // 1024*1024
  bf16* qb  = wpb + 1048576;          // [4,16,2048,64]
  bf16* kb  = qb  + 8388608;          // [4,4,2048,64]
  bf16* vb  = kb  + 2097152;          // [4,4,2048,64]
  bf16* aob = vb  + 2097152;          // [4,2048,1024]

  cast_all<<<10752, 256, 0, stream>>>(x, Wq, Wkv, Wproj, xb, w1b, wpb);
  gemm_qkv<<<dim3(12, 64), 256, 0, stream>>>(xb, w1b, qb, kb, vb);
  attn_alibi<<<dim3(8, 64), 512, 0, stream>>>(qb, kb, vb, aob);
  gemm_proj<<<dim3(8, 64), 256, 0, stream>>>(aob, wpb, bproj, out);
}

// Round 11
// 231.067 us; speedup vs baseline: 1.1124x; 1.1124x over previous
//
#include <hip/hip_runtime.h>
#include <hip/hip_bf16.h>
#include <cstdint>

typedef __bf16 bf16;
typedef bf16 bf16x2 __attribute__((ext_vector_type(2)));
typedef bf16 bf16x4 __attribute__((ext_vector_type(4)));
typedef bf16 bf16x8 __attribute__((ext_vector_type(8)));
typedef float f32x4 __attribute__((ext_vector_type(4)));
typedef unsigned int uint32x2_t __attribute__((ext_vector_type(2)));
typedef unsigned int uint32x4_t __attribute__((ext_vector_type(4)));

#define MFMA16(a, b, c) __builtin_amdgcn_mfma_f32_16x16x32_bf16((a), (b), (c), 0, 0, 0)

// 0.125 * log2(e): folded into Q at the QKV-GEMM epilogue
#define QSCALE 0.18033688011112042f

// async global->LDS DMA, 16B/lane. LDS dest must be wave-uniform base + lane*16.
__device__ inline void async16(const bf16* g, bf16* l) {
  __builtin_amdgcn_global_load_lds(
      (const __attribute__((address_space(1))) void*)g,
      (__attribute__((address_space(3))) void*)l, 16, 0, 0);
}

// ------------------------------------------------------------------
// fused cast fp32 -> bf16 for all four inputs (one launch)
// ------------------------------------------------------------------
__global__ void cast_all(const float* __restrict__ x, const float* __restrict__ wq,
                         const float* __restrict__ wkv, const float* __restrict__ wp,
                         bf16* __restrict__ xb, bf16* __restrict__ w1b,
                         bf16* __restrict__ wpb) {
  const int i = blockIdx.x * blockDim.x + threadIdx.x;
  const float4* src;
  bf16x4* dst;
  int idx;
  if (i < 2097152) {
    src = (const float4*)x; dst = (bf16x4*)xb; idx = i;
  } else if (i < 2359296) {
    src = (const float4*)wq; dst = (bf16x4*)w1b; idx = i - 2097152;
  } else if (i < 2490368) {
    src = (const float4*)wkv; dst = (bf16x4*)(w1b + 1048576); idx = i - 2359296;
  } else {
    src = (const float4*)wp; dst = (bf16x4*)wpb; idx = i - 2490368;
  }
  const float4 v = src[idx];
  bf16x4 o;
  o.x = (bf16)v.x; o.y = (bf16)v.y; o.z = (bf16)v.z; o.w = (bf16)v.w;
  dst[idx] = o;
}

// ------------------------------------------------------------------
// GEMM1: C[m,e] = sum_c x[m,c] * W1[e,c]   (M=8192, N=1536, K=1024)
// XCD swizzle; single-buffer staging; LDS-bounce coalesced epilogue (r9 win).
// Round-11: launch_bounds (256,3) — cap allocator at ~170 total regs/wave
// so 3 blocks/CU fit (CSV VGPR_Count=124 is ARCH-only; acc lives in AGPR;
// gemm total est ~160). LDS 48.9KB x 3 = 146.7 <= 160 OK.
// ------------------------------------------------------------------
__global__ __launch_bounds__(256, 3)
void gemm_qkv(const bf16* __restrict__ A, const bf16* __restrict__ B,
              bf16* __restrict__ qb, bf16* __restrict__ kb, bf16* __restrict__ vb) {
  constexpr int K = 1024;
  constexpr int NX = 12;
  __shared__ bf16 sA[128 * 64];
  __shared__ bf16 sB[128 * 64];
  __shared__ float sC[32 * 132];  // epilogue bounce: 32 rows x 128 e, pad 4
  const int tid = threadIdx.x;
  const int lane = tid & 63, wid = tid >> 6;
  const int col = lane & 15, quad = lane >> 4;
  const int wm = wid >> 1, wn = wid & 1;
  const int bid = blockIdx.y * NX + blockIdx.x;
  const int swz = (bid & 7) * (NX * 64 / 8) + (bid >> 3);
  const int m0 = (swz / NX) * 128, n0 = (swz % NX) * 128;
  const int c7 = col & 7;

  f32x4 acc[4][4];
  const f32x4 z = {0.f, 0.f, 0.f, 0.f};
#pragma unroll
  for (int mi = 0; mi < 4; mi++)
#pragma unroll
    for (int ni = 0; ni < 4; ni++) acc[mi][ni] = z;

  for (int k0 = 0; k0 < K; k0 += 64) {
    __syncthreads();
#pragma unroll
    for (int c = 0; c < 4; ++c) {
      const int idx = c * 256 + tid;
      const int row = idx >> 3, kc = idx & 7;
      const int gkc = kc ^ (row & 7);
      async16(&A[(size_t)(m0 + row) * K + k0 + gkc * 8], &sA[idx * 8]);
      async16(&B[(size_t)(n0 + row) * K + k0 + gkc * 8], &sB[idx * 8]);
    }
    __syncthreads();  // vmcnt(0) drain: DMA complete
#pragma unroll
    for (int ks = 0; ks < 2; ++ks) {
      bf16x8 af[4], bfr[4];
#pragma unroll
      for (int i = 0; i < 4; i++)
        af[i] = *(const bf16x8*)&sA[(wm * 64 + i * 16 + col) * 64 +
                                    (((ks * 4 + quad) ^ c7) << 3)];
#pragma unroll
      for (int i = 0; i < 4; i++)
        bfr[i] = *(const bf16x8*)&sB[(wn * 64 + i * 16 + col) * 64 +
                                     (((ks * 4 + quad) ^ c7) << 3)];
#pragma unroll
      for (int mi = 0; mi < 4; mi++)
#pragma unroll
        for (int ni = 0; ni < 4; ni++)
          acc[mi][ni] = MFMA16(af[mi], bfr[ni], acc[mi][ni]);
    }
  }

  // ---- LDS-bounce epilogue: 4 phases of 32 m-rows ----
  const int erow = tid >> 3, ecg = tid & 7;
  const int gmb = m0 + (erow >> 4) * 64 + (erow & 15);
  const int ge0 = n0 + ecg * 16;
  const float sc = (ge0 < 1024) ? QSCALE : 1.0f;
#pragma unroll
  for (int mi = 0; mi < 4; mi++) {
    __syncthreads();
    {
      const int lrow = wm * 16 + quad * 4;
#pragma unroll
      for (int ni = 0; ni < 4; ni++) {
        const int lcol = wn * 64 + ni * 16 + col;
#pragma unroll
        for (int r = 0; r < 4; r++) sC[(lrow + r) * 132 + lcol] = acc[mi][ni][r];
      }
    }
    __syncthreads();
    const float4 v0 = *(const float4*)&sC[erow * 132 + ecg * 16];
    const float4 v1 = *(const float4*)&sC[erow * 132 + ecg * 16 + 4];
    const float4 v2 = *(const float4*)&sC[erow * 132 + ecg * 16 + 8];
    const float4 v3 = *(const float4*)&sC[erow * 132 + ecg * 16 + 12];
    bf16x8 o0, o1;
    o0[0] = (bf16)(v0.x * sc); o0[1] = (bf16)(v0.y * sc);
    o0[2] = (bf16)(v0.z * sc); o0[3] = (bf16)(v0.w * sc);
    o0[4] = (bf16)(v1.x * sc); o0[5] = (bf16)(v1.y * sc);
    o0[6] = (bf16)(v1.z * sc); o0[7] = (bf16)(v1.w * sc);
    o1[0] = (bf16)(v2.x * sc); o1[1] = (bf16)(v2.y * sc);
    o1[2] = (bf16)(v2.z * sc); o1[3] = (bf16)(v2.w * sc);
    o1[4] = (bf16)(v3.x * sc); o1[5] = (bf16)(v3.y * sc);
    o1[6] = (bf16)(v3.z * sc); o1[7] = (bf16)(v3.w * sc);
    const int m = gmb + mi * 16;
    const int bb = m >> 11, t = m & 2047;
    bf16* dst;
    if (ge0 < 1024) {
      dst = &qb[(((size_t)bb * 16 + (ge0 >> 6)) * 2048 + t) * 64 + (ge0 & 63)];
    } else if (ge0 < 1280) {
      const int f = ge0 - 1024;
      dst = &kb[(((size_t)bb * 4 + (f >> 6)) * 2048 + t) * 64 + (f & 63)];
    } else {
      const int f = ge0 - 1280;
      dst = &vb[(((size_t)bb * 4 + (f >> 6)) * 2048 + t) * 64 + (f & 63)];
    }
    *(bf16x8*)dst = o0;
    *(bf16x8*)(dst + 8) = o1;
  }
}

// ------------------------------------------------------------------
// GEMM2: out[m,e] = sum_c AO[m,c] * Wproj[e,c] + bias[e]  (fp32 out)
// Round-11: launch_bounds (256,3) — same reasoning; LDS 32KB x 3 OK.
// ------------------------------------------------------------------
__global__ __launch_bounds__(256, 3)
void gemm_proj(const bf16* __restrict__ A, const bf16* __restrict__ B,
               const float* __restrict__ bias, float* __restrict__ out) {
  constexpr int K = 1024;
  constexpr int NX = 8;
  __shared__ bf16 sA[128 * 64];
  __shared__ bf16 sB[128 * 64];
  const int tid = threadIdx.x;
  const int lane = tid & 63, wid = tid >> 6;
  const int col = lane & 15, quad = lane >> 4;
  const int wm = wid >> 1, wn = wid & 1;
  const int bid = blockIdx.y * NX + blockIdx.x;
  const int swz = (bid & 7) * (NX * 64 / 8) + (bid >> 3);
  const int m0 = (swz / NX) * 128, n0 = (swz % NX) * 128;
  const int c7 = col & 7;

  f32x4 acc[4][4];
  const f32x4 z = {0.f, 0.f, 0.f, 0.f};
#pragma unroll
  for (int mi = 0; mi < 4; mi++)
#pragma unroll
    for (int ni = 0; ni < 4; ni++) acc[mi][ni] = z;

  for (int k0 = 0; k0 < K; k0 += 64) {
    __syncthreads();
#pragma unroll
    for (int c = 0; c < 4; ++c) {
      const int idx = c * 256 + tid;
      const int row = idx >> 3, kc = idx & 7;
      const int gkc = kc ^ (row & 7);
      async16(&A[(size_t)(m0 + row) * K + k0 + gkc * 8], &sA[idx * 8]);
      async16(&B[(size_t)(n0 + row) * K + k0 + gkc * 8], &sB[idx * 8]);
    }
    __syncthreads();
#pragma unroll
    for (int ks = 0; ks < 2; ++ks) {
      bf16x8 af[4], bfr[4];
#pragma unroll
      for (int i = 0; i < 4; i++)
        af[i] = *(const bf16x8*)&sA[(wm * 64 + i * 16 + col) * 64 +
                                    (((ks * 4 + quad) ^ c7) << 3)];
#pragma unroll
      for (int i = 0; i < 4; i++)
        bfr[i] = *(const bf16x8*)&sB[(wn * 64 + i * 16 + col) * 64 +
                                     (((ks * 4 + quad) ^ c7) << 3)];
#pragma unroll
      for (int mi = 0; mi < 4; mi++)
#pragma unroll
        for (int ni = 0; ni < 4; ni++)
          acc[mi][ni] = MFMA16(af[mi], bfr[ni], acc[mi][ni]);
    }
  }
#pragma unroll
  for (int mi = 0; mi < 4; mi++) {
#pragma unroll
    for (int ni = 0; ni < 4; ni++) {
      const int e = n0 + wn * 64 + ni * 16 + col;
      const float be = bias[e];
#pragma unroll
      for (int r = 0; r < 4; r++) {
        const int m = m0 + wm * 64 + mi * 16 + quad * 4 + r;
        out[(size_t)m * 1024 + e] = acc[mi][ni][r] + be;
      }
    }
  }
}

// ==================================================================
// Flash attention, ALiBi bias, fixed-max softmax, transposed dataflow.
// r7/r9 form, UNCHANGED (measured plateau ~105us across 5 structural
// variants; occupancy pinned at 2 waves/SIMD by arch+AGPR ~200+ regs).
// ==================================================================
#define SM_HALF(kp_)                                                        \
  _Pragma("unroll")                                                         \
  for (int ni = 0; ni < 4; ni++) {                                          \
    unsigned plo[2], phi[2];                                                \
    _Pragma("unroll")                                                       \
    for (int t = 0; t < 2; t++) {                                           \
      const int mi = (kp_) * 2 + t;                                         \
      const int U = c0 + mi * 16 - qbase - ni * 16;                         \
      f32x4 p;                                                              \
      if (U <= -15) {                                                       \
        const float bb = cb * (float)(U + qoff);                            \
        _Pragma("unroll")                                                   \
        for (int r = 0; r < 4; r++)                                         \
          p[r] = __builtin_amdgcn_exp2f(S[mi][ni][r] + (bb + cb * (float)r)); \
      } else if (U >= 16) {                                                 \
        _Pragma("unroll")                                                   \
        for (int r = 0; r < 4; r++)                                         \
          p[r] = __builtin_amdgcn_exp2f(S[mi][ni][r]);                      \
      } else {                                                              \
        const float relf = (float)(U + qoff);                               \
        _Pragma("unroll")                                                   \
        for (int r = 0; r < 4; r++) {                                       \
          const float rr = relf + (float)r;                                 \
          const float bb = (rr <= 0.f) ? cb * rr : 0.f;                     \
          p[r] = __builtin_amdgcn_exp2f(S[mi][ni][r] + bb);                 \
        }                                                                   \
      }                                                                     \
      bf16x2 lo, hi;                                                        \
      lo.x = (bf16)p[0]; lo.y = (bf16)p[1];                                 \
      hi.x = (bf16)p[2]; hi.y = (bf16)p[3];                                 \
      plo[t] = __builtin_bit_cast(unsigned, lo);                            \
      phi[t] = __builtin_bit_cast(unsigned, hi);                            \
    }                                                                       \
    uint32x2_t rl = __builtin_amdgcn_permlane32_swap(plo[0], plo[1], false, false); \
    uint32x2_t rh = __builtin_amdgcn_permlane32_swap(phi[0], phi[1], false, false); \
    uint32x2_t w02 = __builtin_amdgcn_permlane16_swap(rl.x, rl.y, false, false);    \
    uint32x2_t w13 = __builtin_amdgcn_permlane16_swap(rh.x, rh.y, false, false);    \
    uint32x4_t W;                                                           \
    W.x = w02.x; W.y = w13.x; W.z = w02.y; W.w = w13.y;                     \
    ap[ni][kp_] = __builtin_bit_cast(bf16x8, W);                            \
  }

#define PV_HALF(kp_)                                                        \
  {                                                                         \
    bf16x8 bv[4];                                                           \
    _Pragma("unroll")                                                       \
    for (int nd = 0; nd < 4; nd++) {                                        \
      const int d = nd * 16 + col;                                          \
      bv[nd] = *(const bf16x8*)&svw[d * 72 +                                \
                   ((((kp_) * 4 + quad) ^ (d >> 3)) << 3)];                 \
    }                                                                       \
    _Pragma("unroll")                                                       \
    for (int mi = 0; mi < 4; mi++) {                                        \
      _Pragma("unroll")                                                     \
      for (int nd = 0; nd < 4; nd++)                                        \
        O[mi][nd] = MFMA16(ap[mi][kp_], bv[nd], O[mi][nd]);                 \
      Osum[mi] = MFMA16(ap[mi][kp_], bones, Osum[mi]);                      \
    }                                                                       \
  }

__global__ __launch_bounds__(256, 2)
void attn_alibi(const bf16* __restrict__ qb, const bf16* __restrict__ kb,
                const bf16* __restrict__ vb, bf16* __restrict__ ob) {
  __shared__ bf16 sK[2][64 * 64];   // [buf][kv][d], xor-swizzled stride 64 (DMA)
  __shared__ bf16 sVt[2][64 * 72];  // [buf][d][kv], stride 72, kv-block xor-swizzle
  const int tid = threadIdx.x;
  const int lane = tid & 63, wid = tid >> 6;
  const int col = lane & 15, quad = lane >> 4;
  const int c7 = col & 7;
  const int bh = blockIdx.y;
  const int b = bh >> 4, h = bh & 15, kvh = h & 3;
  const int qbase = __builtin_amdgcn_readfirstlane(blockIdx.x * 256 + wid * 64);

  const bf16* qptr = qb + ((size_t)(b * 16 + h) * 2048 + qbase) * 64;
  const bf16* kptr = kb + ((size_t)(b * 4 + kvh) * 2048) * 64;
  const bf16* vptr = vb + ((size_t)(b * 4 + kvh) * 2048) * 64;

  // Q resident as B-operand frags: B[n=q (col)][k=d]
  bf16x8 bq[4][2];
#pragma unroll
  for (int ni = 0; ni < 4; ni++)
#pragma unroll
    for (int ks = 0; ks < 2; ks++)
      bq[ni][ks] = *(const bf16x8*)&qptr[(ni * 16 + col) * 64 + ks * 32 + quad * 8];

  // all-ones B-frag for MFMA row sums
  bf16x8 bones;
#pragma unroll
  for (int j = 0; j < 8; j++) bones[j] = (bf16)1.0f;

  f32x4 O[4][4];
  f32x4 Osum[4];
  const f32x4 z = {0.f, 0.f, 0.f, 0.f};
#pragma unroll
  for (int mi = 0; mi < 4; mi++) {
    Osum[mi] = z;
#pragma unroll
    for (int nd = 0; nd < 4; nd++) O[mi][nd] = z;
  }

  const float cb = exp2f(-0.5f * (float)(h + 1)) * QSCALE;
  const int qoff = quad * 4 - col;

  // staging coords: K rows (tid>>3, +32); V row pair (2*(tid>>3), +1)
  const int rowA = tid >> 3, kc = tid & 7;
  const int kxA = (kc ^ (rowA & 7)) << 3;  // (rowA+32)&7 == rowA&7
  const int rv = rowA * 2;
  const int blkv = rv >> 3, rlv = rv & 7;

  // prologue: K(0) -> sK[0] via DMA; V(0) -> regs
  async16(&kptr[(size_t)rowA * 64 + kxA], &sK[0][tid * 8]);
  async16(&kptr[(size_t)(rowA + 32) * 64 + kxA], &sK[0][(256 + tid) * 8]);
  bf16x8 vr0 = *(const bf16x8*)&vptr[(size_t)rv * 64 + kc * 8];
  bf16x8 vr1 = *(const bf16x8*)&vptr[(size_t)(rv + 1) * 64 + kc * 8];

  int bufi = 0;
  for (int c0 = 0; c0 < 2048; c0 += 64, bufi ^= 1) {
    bf16* skw = sK[bufi];
    bf16* svw = sVt[bufi];
    // commit prefetched V regs to current buffer (transposed, swizzled)
#pragma unroll
    for (int j = 0; j < 8; j++) {
      bf16x2 pr;
      pr.x = vr0[j];
      pr.y = vr1[j];
      *(bf16x2*)&svw[(kc * 8 + j) * 72 + ((blkv ^ kc) << 3) + rlv] = pr;
    }
    __syncthreads();  // single barrier: drains K DMA (vmcnt) + V writes visible

    // issue next chunk's K DMA + V loads — whole compute phase covers latency
    {
      const int cn = (c0 + 64 < 2048) ? c0 + 64 : 0;
      bf16* skn = sK[bufi ^ 1];
      async16(&kptr[(size_t)(cn + rowA) * 64 + kxA], &skn[tid * 8]);
      async16(&kptr[(size_t)(cn + rowA + 32) * 64 + kxA], &skn[(256 + tid) * 8]);
      vr0 = *(const bf16x8*)&vptr[(size_t)(cn + rv) * 64 + kc * 8];
      vr1 = *(const bf16x8*)&vptr[(size_t)(cn + rv + 1) * 64 + kc * 8];
    }

    // S^T = K Q^T : rows=kv, cols=q  (Q pre-scaled: S is in exp2 domain)
    // ks=0 writes fresh accumulators from the constant zero quad
    f32x4 S[4][4];
    {
      bf16x8 ak[4];
#pragma unroll
      for (int mi = 0; mi < 4; mi++)
        ak[mi] = *(const bf16x8*)&skw[(mi * 16 + col) * 64 + ((quad ^ c7) << 3)];
#pragma unroll
      for (int mi = 0; mi < 4; mi++)
#pragma unroll
        for (int ni = 0; ni < 4; ni++)
          S[mi][ni] = MFMA16(ak[mi], bq[ni][0], z);
#pragma unroll
      for (int mi = 0; mi < 4; mi++)
        ak[mi] = *(const bf16x8*)&skw[(mi * 16 + col) * 64 + (((4 + quad) ^ c7) << 3)];
#pragma unroll
      for (int mi = 0; mi < 4; mi++)
#pragma unroll
        for (int ni = 0; ni < 4; ni++)
          S[mi][ni] = MFMA16(ak[mi], bq[ni][1], S[mi][ni]);
    }

    // hazard-free interleave, no scheduler fences:
    // SM(ks1) VALU is register-disjoint from PV(ks0) MFMA sources
    bf16x8 ap[4][2];
    SM_HALF(0);
    PV_HALF(0);
    SM_HALF(1);
    PV_HALF(1);
  }

  // epilogue: every lane holds its row sum in Osum[mi][r]
#pragma unroll
  for (int mi = 0; mi < 4; mi++) {
#pragma unroll
    for (int r = 0; r < 4; r++) {
      const float inv = 1.0f / Osum[mi][r];
      const int t = qbase + mi * 16 + quad * 4 + r;
#pragma unroll
      for (int nd = 0; nd < 4; nd++) {
        ob[((size_t)b * 2048 + t) * 1024 + h * 64 + nd * 16 + col] =
            (bf16)(O[mi][nd][r] * inv);
      }
    }
  }
}

// ------------------------------------------------------------------
extern "C" void kernel_launch(void* const* d_in, const int* in_sizes, int n_in,
                              void* d_out, int out_size, void* d_ws, size_t ws_size,
                              hipStream_t stream) {
  const float* x     = (const float*)d_in[0];
  const float* Wq    = (const float*)d_in[1];
  const float* Wkv   = (const float*)d_in[2];
  const float* Wproj = (const float*)d_in[3];
  const float* bproj = (const float*)d_in[4];
  float* out = (float*)d_out;

  bf16* xb  = (bf16*)d_ws;            // 8192*1024
  bf16* w1b = xb  + 8388608;          // 1536*1024
  bf16* wpb = w1b + 1572864;          // 1024*1024
  bf16* qb  = wpb + 1048576;          // [4,16,2048,64]
  bf16* kb  = qb  + 8388608;          // [4,4,2048,64]
  bf16* vb  = kb  + 2097152;          // [4,4,2048,64]
  bf16* aob = vb  + 2097152;          // [4,2048,1024]

  cast_all<<<10752, 256, 0, stream>>>(x, Wq, Wkv, Wproj, xb, w1b, wpb);
  gemm_qkv<<<dim3(12, 64), 256, 0, stream>>>(xb, w1b, qb, kb, vb);
  attn_alibi<<<dim3(8, 64), 256, 0, stream>>>(qb, kb, vb, aob);
  gemm_proj<<<dim3(8, 64), 256, 0, stream>>>(aob, wpb, bproj, out);
}